// Round 1
// baseline (935.613 us; speedup 1.0000x reference)
//
#include <hip/hip_runtime.h>

#define BB 256
#define LL 64
#define DD 1024
#define TD 62          // data columns per tile (plus 1 halo each side -> 64 LDS cols)
#define NT 17          // ceil(1024/62) = 17 (16 full tiles + one 32-col tile)

__global__ __launch_bounds__(256, 3)
void fused_cc_kernel(const float* __restrict__ left,
                     const float* __restrict__ right,
                     const float* __restrict__ Wl,
                     const float* __restrict__ bl,
                     const float* __restrict__ Wr,
                     const float* __restrict__ br,
                     const float* __restrict__ Wconv,
                     float* __restrict__ out) {
    __shared__ float bufL[64][64];   // left'
    __shared__ float bufR[64][64];   // right'
    __shared__ float bufX[64][64];   // raw staging, then corr halves

    const int tid  = threadIdx.x;
    const int lane = tid & 63;
    const int w    = __builtin_amdgcn_readfirstlane(tid >> 6);   // wave id 0..3, sgpr

    const int b       = blockIdx.y;
    const int t       = blockIdx.x;
    const int d_start = t * TD;
    const int ncols   = min(TD, DD - d_start);     // 62 or 32 (last tile)

    const int  g        = d_start - 1 + lane;      // global d for LDS column=lane
    const bool colvalid = (g >= 0) && (g < DD);

    const float* lbase = left  + (size_t)b * LL * DD;
    const float* rbase = right + (size_t)b * LL * DD;

    // ---- stage 1: load left raw -> bufX (coalesced: lane <-> d)
    for (int i = 0; i < 16; ++i) {
        int l = w * 16 + i;
        bufX[l][lane] = colvalid ? lbase[l * DD + g] : 0.0f;
    }
    __syncthreads();

    // ---- stage 2: left' = Wl @ left + bl  -> bufL
    {
        float acc[16];
#pragma unroll
        for (int ii = 0; ii < 16; ++ii) acc[ii] = bl[w + 4 * ii];
        for (int l = 0; l < 64; ++l) {
            float x = bufX[l][lane];
#pragma unroll
            for (int ii = 0; ii < 16; ++ii) {
                int k = w + 4 * ii;                // wave-uniform -> scalar loads
                acc[ii] += Wl[k * 64 + l] * x;
            }
        }
#pragma unroll
        for (int ii = 0; ii < 16; ++ii) bufL[w + 4 * ii][lane] = acc[ii];
    }
    __syncthreads();

    // ---- stage 3: load right raw -> bufX
    for (int i = 0; i < 16; ++i) {
        int l = w * 16 + i;
        bufX[l][lane] = colvalid ? rbase[l * DD + g] : 0.0f;
    }
    __syncthreads();

    // ---- stage 4: right' = Wr @ right + br -> bufR
    {
        float acc[16];
#pragma unroll
        for (int ii = 0; ii < 16; ++ii) acc[ii] = br[w + 4 * ii];
        for (int l = 0; l < 64; ++l) {
            float x = bufX[l][lane];
#pragma unroll
            for (int ii = 0; ii < 16; ++ii) {
                int k = w + 4 * ii;
                acc[ii] += Wr[k * 64 + l] * x;
            }
        }
#pragma unroll
        for (int ii = 0; ii < 16; ++ii) bufR[w + 4 * ii][lane] = acc[ii];
    }
    __syncthreads();

    // ---- stages 5..8: corr halves into bufX, conv accumulated in registers
    float yacc[16];
#pragma unroll
    for (int ii = 0; ii < 16; ++ii) yacc[ii] = 0.0f;

    const int col0 = min(lane, TD - 1);            // clamp so col0+2 <= 63

    // ===== half A: shifts i in [0,64): corr[i] = sum_{j=0..i} L'[j]*R'[j+63-i]
    {
        float acc[16];
#pragma unroll
        for (int ii = 0; ii < 16; ++ii) {
            int i = w + 4 * ii;
            float a = 0.0f;
            for (int j = 0; j <= i; ++j)
                a += bufL[j][lane] * bufR[j + 63 - i][lane];
            acc[ii] = colvalid ? a : 0.0f;
        }
#pragma unroll
        for (int ii = 0; ii < 16; ++ii) bufX[w + 4 * ii][lane] = acc[ii];
    }
    __syncthreads();

    // conv accumulate, corr rows c_global = ci (half A)
    for (int ci = 0; ci < 64; ++ci) {
        float v0 = bufX[ci][col0];
        float v1 = bufX[ci][col0 + 1];
        float v2 = bufX[ci][col0 + 2];
#pragma unroll
        for (int ii = 0; ii < 16; ++ii) {
            int k = w + 4 * ii;                          // wave-uniform
            const float* wp = Wconv + ((size_t)k * 128 + ci) * 3;
            yacc[ii] += wp[0] * v0 + wp[1] * v1 + wp[2] * v2;
        }
    }
    __syncthreads();

    // ===== half B: shifts i in [64,128): corr[i] = sum_{j=i-63..63} L'[j]*R'[j+63-i]
    {
        float acc[16];
#pragma unroll
        for (int ii = 0; ii < 16; ++ii) {
            int ig = 64 + w + 4 * ii;                    // global shift index
            float a = 0.0f;
            for (int j = ig - 63; j < 64; ++j)
                a += bufL[j][lane] * bufR[j + 63 - ig][lane];
            acc[ii] = colvalid ? a : 0.0f;               // ig=127 -> empty -> 0
        }
        __syncthreads();                                  // conv half A done reading bufX
#pragma unroll
        for (int ii = 0; ii < 16; ++ii) bufX[w + 4 * ii][lane] = acc[ii];
    }
    __syncthreads();

    // conv accumulate, corr rows c_global = 64 + ci (half B)
    for (int ci = 0; ci < 64; ++ci) {
        float v0 = bufX[ci][col0];
        float v1 = bufX[ci][col0 + 1];
        float v2 = bufX[ci][col0 + 2];
        int cg = 64 + ci;
#pragma unroll
        for (int ii = 0; ii < 16; ++ii) {
            int k = w + 4 * ii;
            const float* wp = Wconv + ((size_t)k * 128 + cg) * 3;
            yacc[ii] += wp[0] * v0 + wp[1] * v1 + wp[2] * v2;
        }
    }

    // ---- store y[b, k, d_start+lane]
    if (lane < ncols) {
#pragma unroll
        for (int ii = 0; ii < 16; ++ii) {
            int k = w + 4 * ii;
            out[((size_t)b * LL + k) * DD + d_start + lane] = yacc[ii];
        }
    }
}

extern "C" void kernel_launch(void* const* d_in, const int* in_sizes, int n_in,
                              void* d_out, int out_size, void* d_ws, size_t ws_size,
                              hipStream_t stream) {
    const float* left  = (const float*)d_in[0];
    const float* right = (const float*)d_in[1];
    const float* Wl    = (const float*)d_in[2];
    const float* bl    = (const float*)d_in[3];
    const float* Wr    = (const float*)d_in[4];
    const float* br    = (const float*)d_in[5];
    const float* Wconv = (const float*)d_in[6];
    float* out = (float*)d_out;

    dim3 grid(NT, BB);
    fused_cc_kernel<<<grid, dim3(256), 0, stream>>>(left, right, Wl, bl, Wr, br,
                                                    Wconv, out);
}

// Round 2
// 853.536 us; speedup vs baseline: 1.0962x; 1.0962x over previous
//
#include <hip/hip_runtime.h>

#define BB 256
#define LL 64
#define DD 1024
#define TD 62          // valid output columns per tile (64 LDS cols incl. 1 halo each side)
#define NT 17          // ceil(1024/62)

// corr half A: shifts i = 16W+ii (ii in [0,16)), corr[i] = sum_{j=0..i} L'[j]*R'[j+63-i]
template<int W>
__device__ __forceinline__ void corrA(const float (&L)[64][64], const float (&R)[64],
                                      float (&acc)[16], int lane) {
#pragma unroll
    for (int ii = 0; ii < 16; ++ii) acc[ii] = 0.0f;
#pragma unroll
    for (int j = 0; j < 64; ++j) {
        if (j <= 16 * W + 15) {               // compile-time prune
            float Lj = L[j][lane];
#pragma unroll
            for (int ii = 0; ii < 16; ++ii) {
                const int i = 16 * W + ii;
                if (j <= i) acc[ii] += Lj * R[j + 63 - i];   // constant reg index
            }
        }
    }
}

// corr half B: shifts ig = 64+16W+ii, corr[ig] = sum_{j=ig-63..63} L'[j]*R'[j+63-ig]
template<int W>
__device__ __forceinline__ void corrB(const float (&L)[64][64], const float (&R)[64],
                                      float (&acc)[16], int lane) {
#pragma unroll
    for (int ii = 0; ii < 16; ++ii) acc[ii] = 0.0f;
#pragma unroll
    for (int j = 0; j < 64; ++j) {
        if (j >= 16 * W + 1) {                // compile-time prune (smallest ig-63)
            float Lj = L[j][lane];
#pragma unroll
            for (int ii = 0; ii < 16; ++ii) {
                const int ig = 64 + 16 * W + ii;
                if (j >= ig - 63) acc[ii] += Lj * R[j + 63 - ig];  // idx = j-1-16W-ii
            }
        }
    }
}

__global__ __launch_bounds__(256, 3)
void fused_cc_kernel(const float* __restrict__ left,
                     const float* __restrict__ right,
                     const float* __restrict__ Wl,
                     const float* __restrict__ bl,
                     const float* __restrict__ Wr,
                     const float* __restrict__ br,
                     const float* __restrict__ Wconv,
                     float* __restrict__ out) {
    __shared__ float buf0[64][64];   // left raw -> L'
    __shared__ float buf1[64][64];   // right raw -> R'
    __shared__ float buf2[64][64];   // corr halves

    const int tid  = threadIdx.x;
    const int lane = tid & 63;
    const int w    = __builtin_amdgcn_readfirstlane(tid >> 6);  // wave id, sgpr
    const int kw   = 16 * w;                                    // wave's k/row base

    const int b       = blockIdx.y;
    const int d_start = blockIdx.x * TD;
    const int ncols   = min(TD, DD - d_start);

    const int  g        = d_start - 1 + lane;     // global d for LDS column = lane
    const bool colvalid = (g >= 0) && (g < DD);

    const float* lbase = left  + (size_t)b * LL * DD;
    const float* rbase = right + (size_t)b * LL * DD;

    // ---- phase 1: stage both inputs (overlapped global latency)
#pragma unroll
    for (int i = 0; i < 16; ++i) {
        int l = kw + i;
        buf0[l][lane] = colvalid ? lbase[l * DD + g] : 0.0f;
        buf1[l][lane] = colvalid ? rbase[l * DD + g] : 0.0f;
    }
    __syncthreads();

    // ---- phase 2: both GEMMs into registers (k = kw+ii, wave-uniform -> s_loads)
    float accL[16], accR[16];
#pragma unroll
    for (int ii = 0; ii < 16; ++ii) { accL[ii] = bl[kw + ii]; accR[ii] = br[kw + ii]; }
#pragma unroll 4
    for (int l = 0; l < 64; ++l) {
        float x0 = buf0[l][lane];
        float x1 = buf1[l][lane];
#pragma unroll
        for (int ii = 0; ii < 16; ++ii) {
            accL[ii] += Wl[(kw + ii) * 64 + l] * x0;
            accR[ii] += Wr[(kw + ii) * 64 + l] * x1;
        }
    }
    __syncthreads();            // all raw reads done before in-place overwrite

    // ---- phase 3: write L' -> buf0, R' -> buf1
#pragma unroll
    for (int ii = 0; ii < 16; ++ii) {
        buf0[kw + ii][lane] = accL[ii];
        buf1[kw + ii][lane] = accR[ii];
    }
    __syncthreads();

    // ---- phase 4: preload R' column into registers (constant indices -> VGPRs)
    float R[64];
#pragma unroll
    for (int j = 0; j < 64; ++j) R[j] = buf1[j][lane];

    float yacc[16];
#pragma unroll
    for (int ii = 0; ii < 16; ++ii) yacc[ii] = 0.0f;

    const int col0 = min(lane, TD - 1);

    // ---- phase 5: corr half A (templated on wave id; no barriers inside)
    {
        float acc[16];
        switch (w) {
            case 0: corrA<0>(buf0, R, acc, lane); break;
            case 1: corrA<1>(buf0, R, acc, lane); break;
            case 2: corrA<2>(buf0, R, acc, lane); break;
            default: corrA<3>(buf0, R, acc, lane); break;
        }
#pragma unroll
        for (int ii = 0; ii < 16; ++ii)
            buf2[kw + ii][lane] = colvalid ? acc[ii] : 0.0f;
    }
    __syncthreads();

    // ---- phase 6: conv accumulate over corr rows c = 0..63
#pragma unroll 2
    for (int ci = 0; ci < 64; ++ci) {
        float v0 = buf2[ci][col0];
        float v1 = buf2[ci][col0 + 1];
        float v2 = buf2[ci][col0 + 2];
#pragma unroll
        for (int ii = 0; ii < 16; ++ii) {
            const float* wp = Wconv + ((kw + ii) * 128 + ci) * 3;   // uniform -> s_load
            yacc[ii] += wp[0] * v0 + wp[1] * v1 + wp[2] * v2;
        }
    }
    __syncthreads();            // conv reads done before buf2 overwrite

    // ---- phase 7: corr half B
    {
        float acc[16];
        switch (w) {
            case 0: corrB<0>(buf0, R, acc, lane); break;
            case 1: corrB<1>(buf0, R, acc, lane); break;
            case 2: corrB<2>(buf0, R, acc, lane); break;
            default: corrB<3>(buf0, R, acc, lane); break;
        }
#pragma unroll
        for (int ii = 0; ii < 16; ++ii)
            buf2[kw + ii][lane] = colvalid ? acc[ii] : 0.0f;
    }
    __syncthreads();

    // ---- phase 8: conv accumulate over corr rows c = 64..127
#pragma unroll 2
    for (int ci = 0; ci < 64; ++ci) {
        float v0 = buf2[ci][col0];
        float v1 = buf2[ci][col0 + 1];
        float v2 = buf2[ci][col0 + 2];
        int c = 64 + ci;
#pragma unroll
        for (int ii = 0; ii < 16; ++ii) {
            const float* wp = Wconv + ((kw + ii) * 128 + c) * 3;
            yacc[ii] += wp[0] * v0 + wp[1] * v1 + wp[2] * v2;
        }
    }

    // ---- phase 9: store y[b, k, d_start+lane]
    if (lane < ncols) {
#pragma unroll
        for (int ii = 0; ii < 16; ++ii)
            out[((size_t)b * LL + (kw + ii)) * DD + d_start + lane] = yacc[ii];
    }
}

extern "C" void kernel_launch(void* const* d_in, const int* in_sizes, int n_in,
                              void* d_out, int out_size, void* d_ws, size_t ws_size,
                              hipStream_t stream) {
    const float* left  = (const float*)d_in[0];
    const float* right = (const float*)d_in[1];
    const float* Wl    = (const float*)d_in[2];
    const float* bl    = (const float*)d_in[3];
    const float* Wr    = (const float*)d_in[4];
    const float* br    = (const float*)d_in[5];
    const float* Wconv = (const float*)d_in[6];
    float* out = (float*)d_out;

    dim3 grid(NT, BB);
    fused_cc_kernel<<<grid, dim3(256), 0, stream>>>(left, right, Wl, bl, Wr, br,
                                                    Wconv, out);
}

// Round 3
// 452.342 us; speedup vs baseline: 2.0684x; 1.8869x over previous
//
#include <hip/hip_runtime.h>

#define BB 256
#define LL 64
#define DD 1024
#define TD 62          // valid output columns per tile (64 LDS cols incl. 1 halo each side)
#define NT 17          // ceil(1024/62)
#define CP 72          // corrT pitch in bf16 elements (row stride 144 B, 16B-aligned)

typedef __attribute__((ext_vector_type(8))) short short8;
typedef __attribute__((ext_vector_type(4))) float float4_;

__device__ __forceinline__ unsigned short f2bf(float f) {
    union { float f; unsigned u; } v; v.f = f;
    unsigned u = v.u;
    return (unsigned short)((u + 0x7fffu + ((u >> 16) & 1u)) >> 16);  // RNE
}

// ---- prep: repack Wconv[k][c][t] (fp32) into per-lane A-fragment layout (bf16)
// W2[t][q][w][lane][j] : lane m=lane&15, quad=lane>>4 ; k=16w+m ; c=32q+8*quad+j
__global__ void prep_wconv(const float* __restrict__ Wconv, unsigned short* __restrict__ W2) {
    int o = blockIdx.x * 256 + threadIdx.x;          // 0..24575
    int j    = o & 7;
    int lane = (o >> 3) & 63;
    int w    = (o >> 9) & 3;
    int q    = (o >> 11) & 3;
    int t    = o >> 13;
    int m = lane & 15, quad = lane >> 4;
    int krow = 16 * w + m;
    int c    = 32 * q + 8 * quad + j;
    W2[o] = f2bf(Wconv[(krow * 128 + c) * 3 + t]);
}

// corr half A: shifts i = 16W+ii, corr[i] = sum_{j=0..i} L'[j]*R'[j+63-i]
template<int W>
__device__ __forceinline__ void corrA(const float (&L)[64][64], const float (&R)[64],
                                      float (&acc)[16], int lane) {
#pragma unroll
    for (int ii = 0; ii < 16; ++ii) acc[ii] = 0.0f;
#pragma unroll
    for (int j = 0; j < 64; ++j) {
        if (j <= 16 * W + 15) {
            float Lj = L[j][lane];
#pragma unroll
            for (int ii = 0; ii < 16; ++ii) {
                const int i = 16 * W + ii;
                if (j <= i) acc[ii] += Lj * R[j + 63 - i];
            }
        }
    }
}

// corr half B: shifts ig = 64+16W+ii, corr[ig] = sum_{j=ig-63..63} L'[j]*R'[j+63-ig]
template<int W>
__device__ __forceinline__ void corrB(const float (&L)[64][64], const float (&R)[64],
                                      float (&acc)[16], int lane) {
#pragma unroll
    for (int ii = 0; ii < 16; ++ii) acc[ii] = 0.0f;
#pragma unroll
    for (int j = 0; j < 64; ++j) {
        if (j >= 16 * W + 1) {
            float Lj = L[j][lane];
#pragma unroll
            for (int ii = 0; ii < 16; ++ii) {
                const int ig = 64 + 16 * W + ii;
                if (j >= ig - 63) acc[ii] += Lj * R[j + 63 - ig];
            }
        }
    }
}

template<bool PRE>
__device__ __forceinline__ short8 load_afrag(const float* __restrict__ Wconv,
                                             const unsigned short* __restrict__ W2,
                                             int t, int qg, int w, int lane) {
    if (PRE) {
        return ((const short8*)W2)[((t * 4 + qg) * 4 + w) * 64 + lane];
    } else {
        int m = lane & 15, quad = lane >> 4;
        const float* p = Wconv + ((16 * w + m) * 128 + 32 * qg + 8 * quad) * 3 + t;
        short8 r;
#pragma unroll
        for (int j = 0; j < 8; ++j) r[j] = (short)f2bf(p[3 * j]);
        return r;
    }
}

template<bool PRE>
__global__ __launch_bounds__(256, 3)
void fused_cc_kernel(const float* __restrict__ left,
                     const float* __restrict__ right,
                     const float* __restrict__ Wl,
                     const float* __restrict__ bl,
                     const float* __restrict__ Wr,
                     const float* __restrict__ br,
                     const float* __restrict__ Wconv,
                     const unsigned short* __restrict__ W2,
                     float* __restrict__ out) {
    __shared__ float buf0[64][64];                 // left raw -> L'
    __shared__ float buf1[64][64];                 // right raw -> R'
    __shared__ unsigned short corrT[66 * CP];      // corr^T bf16: [col-lane][c_local]

    const int tid  = threadIdx.x;
    const int lane = tid & 63;
    const int w    = __builtin_amdgcn_readfirstlane(tid >> 6);
    const int kw   = 16 * w;
    const int m16  = lane & 15;
    const int quad = lane >> 4;

    const int b       = blockIdx.y;
    const int d_start = blockIdx.x * TD;
    const int ncols   = min(TD, DD - d_start);

    const int  g        = d_start - 1 + lane;      // global d for LDS column = lane
    const bool colvalid = (g >= 0) && (g < DD);

    const float* lbase = left  + (size_t)b * LL * DD;
    const float* rbase = right + (size_t)b * LL * DD;

    // zero corrT rows 64,65 (read as B-operand halo rows, never written by corr)
    if (tid < 72) ((unsigned*)corrT)[64 * (CP / 2) + tid] = 0u;

    // ---- phase 1: stage both inputs
#pragma unroll
    for (int i = 0; i < 16; ++i) {
        int l = kw + i;
        buf0[l][lane] = colvalid ? lbase[l * DD + g] : 0.0f;
        buf1[l][lane] = colvalid ? rbase[l * DD + g] : 0.0f;
    }
    __syncthreads();

    // ---- phase 2: both linears into registers (fp32 VALU, scalar weights)
    float accL[16], accR[16];
#pragma unroll
    for (int ii = 0; ii < 16; ++ii) { accL[ii] = bl[kw + ii]; accR[ii] = br[kw + ii]; }
#pragma unroll 4
    for (int l = 0; l < 64; ++l) {
        float x0 = buf0[l][lane];
        float x1 = buf1[l][lane];
#pragma unroll
        for (int ii = 0; ii < 16; ++ii) {
            accL[ii] += Wl[(kw + ii) * 64 + l] * x0;
            accR[ii] += Wr[(kw + ii) * 64 + l] * x1;
        }
    }
    __syncthreads();

    // ---- phase 3: write L' -> buf0, R' -> buf1
#pragma unroll
    for (int ii = 0; ii < 16; ++ii) {
        buf0[kw + ii][lane] = accL[ii];
        buf1[kw + ii][lane] = accR[ii];
    }
    __syncthreads();

    // ---- phase 4: preload R' column into registers
    float R[64];
#pragma unroll
    for (int j = 0; j < 64; ++j) R[j] = buf1[j][lane];

    float4_ yacc[4];
#pragma unroll
    for (int nt = 0; nt < 4; ++nt) yacc[nt] = (float4_){0.f, 0.f, 0.f, 0.f};

    // ---- phase 5: corr half A -> corrT (bf16, transposed: row=col-lane, c contiguous)
    {
        float acc[16];
        switch (w) {
            case 0: corrA<0>(buf0, R, acc, lane); break;
            case 1: corrA<1>(buf0, R, acc, lane); break;
            case 2: corrA<2>(buf0, R, acc, lane); break;
            default: corrA<3>(buf0, R, acc, lane); break;
        }
        unsigned* cw = (unsigned*)&corrT[lane * CP + kw];
#pragma unroll
        for (int ii = 0; ii < 16; ii += 2) {
            unsigned lo = colvalid ? (unsigned)f2bf(acc[ii])     : 0u;
            unsigned hi = colvalid ? (unsigned)f2bf(acc[ii + 1]) : 0u;
            cw[ii >> 1] = lo | (hi << 16);
        }
    }
    __syncthreads();

    // ---- phase 6: conv MFMA, c_global 0..63 (A-frag q = 0,1)
    {
        short8 af[6];
#pragma unroll
        for (int t = 0; t < 3; ++t)
#pragma unroll
            for (int qi = 0; qi < 2; ++qi)
                af[t * 2 + qi] = load_afrag<PRE>(Wconv, W2, t, qi, w, lane);
#pragma unroll
        for (int t = 0; t < 3; ++t)
#pragma unroll
            for (int qi = 0; qi < 2; ++qi) {
                const int cb = 32 * qi + 8 * quad;
#pragma unroll
                for (int nt = 0; nt < 4; ++nt) {
                    const int row = nt * 16 + m16 + t;
                    short8 bf = *(const short8*)&corrT[row * CP + cb];
                    yacc[nt] = __builtin_amdgcn_mfma_f32_16x16x32_bf16(af[t * 2 + qi], bf,
                                                                       yacc[nt], 0, 0, 0);
                }
            }
    }
    // prefetch A-frags for half B (independent of the barrier below)
    short8 af2[6];
#pragma unroll
    for (int t = 0; t < 3; ++t)
#pragma unroll
        for (int qi = 0; qi < 2; ++qi)
            af2[t * 2 + qi] = load_afrag<PRE>(Wconv, W2, t, 2 + qi, w, lane);
    __syncthreads();                 // conv reads done before corrT overwrite

    // ---- phase 7: corr half B -> corrT (c_local = c_global - 64)
    {
        float acc[16];
        switch (w) {
            case 0: corrB<0>(buf0, R, acc, lane); break;
            case 1: corrB<1>(buf0, R, acc, lane); break;
            case 2: corrB<2>(buf0, R, acc, lane); break;
            default: corrB<3>(buf0, R, acc, lane); break;
        }
        unsigned* cw = (unsigned*)&corrT[lane * CP + kw];
#pragma unroll
        for (int ii = 0; ii < 16; ii += 2) {
            unsigned lo = colvalid ? (unsigned)f2bf(acc[ii])     : 0u;
            unsigned hi = colvalid ? (unsigned)f2bf(acc[ii + 1]) : 0u;
            cw[ii >> 1] = lo | (hi << 16);
        }
    }
    __syncthreads();

    // ---- phase 8: conv MFMA, c_global 64..127 (A-frag q = 2,3)
#pragma unroll
    for (int t = 0; t < 3; ++t)
#pragma unroll
        for (int qi = 0; qi < 2; ++qi) {
            const int cb = 32 * qi + 8 * quad;
#pragma unroll
            for (int nt = 0; nt < 4; ++nt) {
                const int row = nt * 16 + m16 + t;
                short8 bf = *(const short8*)&corrT[row * CP + cb];
                yacc[nt] = __builtin_amdgcn_mfma_f32_16x16x32_bf16(af2[t * 2 + qi], bf,
                                                                   yacc[nt], 0, 0, 0);
            }
        }

    // ---- phase 9: store y[b, k, d]  (D layout: col=lane&15, row=quad*4+r)
#pragma unroll
    for (int nt = 0; nt < 4; ++nt) {
        const int dd = nt * 16 + m16;
        if (dd < ncols) {
#pragma unroll
            for (int r = 0; r < 4; ++r) {
                int k = kw + 4 * quad + r;
                out[((size_t)b * LL + k) * DD + d_start + dd] = yacc[nt][r];
            }
        }
    }
}

extern "C" void kernel_launch(void* const* d_in, const int* in_sizes, int n_in,
                              void* d_out, int out_size, void* d_ws, size_t ws_size,
                              hipStream_t stream) {
    const float* left  = (const float*)d_in[0];
    const float* right = (const float*)d_in[1];
    const float* Wl    = (const float*)d_in[2];
    const float* bl    = (const float*)d_in[3];
    const float* Wr    = (const float*)d_in[4];
    const float* br    = (const float*)d_in[5];
    const float* Wconv = (const float*)d_in[6];
    float* out = (float*)d_out;

    dim3 grid(NT, BB);
    if (ws_size >= 24576 * sizeof(unsigned short)) {
        unsigned short* W2 = (unsigned short*)d_ws;
        prep_wconv<<<96, 256, 0, stream>>>(Wconv, W2);
        fused_cc_kernel<true><<<grid, dim3(256), 0, stream>>>(left, right, Wl, bl, Wr, br,
                                                              Wconv, W2, out);
    } else {
        fused_cc_kernel<false><<<grid, dim3(256), 0, stream>>>(left, right, Wl, bl, Wr, br,
                                                               Wconv, nullptr, out);
    }
}

// Round 4
// 252.027 us; speedup vs baseline: 3.7124x; 1.7948x over previous
//
#include <hip/hip_runtime.h>

#define DD 1024
#define TD 62          // valid output columns per tile (64 LDS cols incl. 1 halo each side)
#define NTILE 17       // ceil(1024/62)
#define BB 256

typedef __attribute__((ext_vector_type(8))) short short8;
typedef __attribute__((ext_vector_type(4))) float float4_;

__device__ __forceinline__ unsigned short f2bf(float f) {
    union { float f; unsigned u; } v; v.f = f;
    unsigned u = v.u;
    return (unsigned short)((u + 0x7fffu + ((u >> 16) & 1u)) >> 16);  // RNE
}
__device__ __forceinline__ unsigned pack2(float a, float b) {
    return (unsigned)f2bf(a) | ((unsigned)f2bf(b) << 16);
}

// ws (bf16 elements): [0,24576) conv A-frags  W2c[t][q][w][lane][j]
//                     [24576,32768) linear A-frags Wf[mat][l0s][mt][lane][j]
__global__ void prep_w(const float* __restrict__ Wconv,
                       const float* __restrict__ Wl,
                       const float* __restrict__ Wr,
                       unsigned short* __restrict__ W2) {
    int o = blockIdx.x * 256 + threadIdx.x;          // 0..32767
    if (o < 24576) {
        int j = o & 7, lane = (o >> 3) & 63, w = (o >> 9) & 3, q = (o >> 11) & 3, t = o >> 13;
        int m = lane & 15, quad = lane >> 4;
        int k = 16 * w + m, c = 32 * q + 8 * quad + j;
        W2[o] = f2bf(Wconv[(k * 128 + c) * 3 + t]);
    } else {
        int o2 = o - 24576;
        int j = o2 & 7, lane = (o2 >> 3) & 63, mt = (o2 >> 9) & 3,
            l0s = (o2 >> 11) & 1, mat = (o2 >> 12) & 1;
        int m = lane & 15, quad = lane >> 4;
        int k = 16 * mt + m, l = 32 * l0s + quad * 8 + j;
        const float* src = mat ? Wr : Wl;
        W2[o] = f2bf(src[k * 64 + l]);
    }
}

// merged corr: for ii in [0,16): i = 16W+ii
//   accA[ii] = corr[i]    = sum_{j=0..i}   L[j]*R[j+63-i]
//   accB[ii] = corr[i+64] = sum_{j=i+1..63} L[j]*R[j-1-i]
// each (accA,accB) pair is exactly 64 FMAs -> perfectly balanced across waves
template<int W>
__device__ __forceinline__ void corrAB(const float (&L)[64][64], const float (&Rr)[64],
                                       float (&accA)[16], float (&accB)[16], int lane) {
#pragma unroll
    for (int ii = 0; ii < 16; ++ii) { accA[ii] = 0.0f; accB[ii] = 0.0f; }
#pragma unroll
    for (int j = 0; j < 64; ++j) {
        float Lj = L[j][lane];
#pragma unroll
        for (int ii = 0; ii < 16; ++ii) {
            const int i = 16 * W + ii;
            if (j <= i) accA[ii] += Lj * Rr[j + 63 - i];
            else        accB[ii] += Lj * Rr[j - 1 - i];
        }
    }
}

template<bool PRE>
__global__ __launch_bounds__(256, 3)
void fused_cc_kernel(const float* __restrict__ left,
                     const float* __restrict__ right,
                     const float* __restrict__ Wl,
                     const float* __restrict__ bl,
                     const float* __restrict__ Wr,
                     const float* __restrict__ br,
                     const float* __restrict__ Wconv,
                     const unsigned short* __restrict__ W2,
                     float* __restrict__ out) {
    __shared__ float bufL[64][64];        // L' fp32
    __shared__ float bufR[64][64];        // R' fp32
    __shared__ unsigned sh[4224];         // staging xL[2048]+xR[2048]  |  corrT bf16 [66][128]

    unsigned* xL = sh;                    // [lpair 32][d 64] dwords (2 bf16 l's per dword)
    unsigned* xR = sh + 2048;
    unsigned short* corrT = (unsigned short*)sh;   // row=d (0..65), col=c, 16B-group swizzle

    const int tid  = threadIdx.x;
    const int lane = tid & 63;
    const int w    = __builtin_amdgcn_readfirstlane(tid >> 6);
    const int kw   = 16 * w;
    const int m16  = lane & 15;
    const int quad = lane >> 4;

    const int b       = blockIdx.y;
    const int d_start = blockIdx.x * TD;
    const int ncols   = min(TD, DD - d_start);

    const int  g        = d_start - 1 + lane;      // global d for local column = lane
    const bool colvalid = (g >= 0) && (g < DD);

    // halo rows 64,65 of corrT live past the staging region (dwords 4096..4223): zero now
    if (tid < 128) sh[4096 + tid] = 0u;

    const float* lb = left  + (size_t)b * 64 * DD;
    const float* rb = right + (size_t)b * 64 * DD;

    // ---- P1: stage both inputs as bf16 l-pairs (coalesced global, conflict-free LDS)
#pragma unroll
    for (int i = 0; i < 8; ++i) {
        int p = 8 * w + i, l = 2 * p;
        float a0 = colvalid ? lb[l * DD + g] : 0.0f;
        float a1 = colvalid ? lb[(l + 1) * DD + g] : 0.0f;
        float c0 = colvalid ? rb[l * DD + g] : 0.0f;
        float c1 = colvalid ? rb[(l + 1) * DD + g] : 0.0f;
        xL[p * 64 + lane] = pack2(a0, a1);
        xR[p * 64 + lane] = pack2(c0, c1);
    }
    __syncthreads();

    // ---- P2: both linears via MFMA (A = W frags, B = staged input), M=64,N=64,K=64
    short8 afL[2], afR[2];
    if (PRE) {
        const short8* Wf = (const short8*)(W2 + 24576);
        afL[0] = Wf[(0 * 4 + w) * 64 + lane];      // [mat0][l0s0][mt=w]
        afL[1] = Wf[(1 * 4 + w) * 64 + lane];      // [mat0][l0s1]
        afR[0] = Wf[(2 * 4 + w) * 64 + lane];      // [mat1][l0s0]
        afR[1] = Wf[(3 * 4 + w) * 64 + lane];      // [mat1][l0s1]
    } else {
#pragma unroll
        for (int l0s = 0; l0s < 2; ++l0s) {
            const float* pL = Wl + (kw + m16) * 64 + 32 * l0s + quad * 8;
            const float* pR = Wr + (kw + m16) * 64 + 32 * l0s + quad * 8;
#pragma unroll
            for (int j = 0; j < 8; ++j) {
                afL[l0s][j] = (short)f2bf(pL[j]);
                afR[l0s][j] = (short)f2bf(pR[j]);
            }
        }
    }
    float4_ accL[4], accR[4];
#pragma unroll
    for (int nt = 0; nt < 4; ++nt) { accL[nt] = (float4_){0,0,0,0}; accR[nt] = (float4_){0,0,0,0}; }
#pragma unroll
    for (int l0s = 0; l0s < 2; ++l0s)
#pragma unroll
        for (int nt = 0; nt < 4; ++nt) {
            union { unsigned u[4]; short8 s; } tL, tR;
#pragma unroll
            for (int jj = 0; jj < 4; ++jj) {
                int a = (l0s * 16 + quad * 4 + jj) * 64 + nt * 16 + m16;
                tL.u[jj] = xL[a];
                tR.u[jj] = xR[a];
            }
            accL[nt] = __builtin_amdgcn_mfma_f32_16x16x32_bf16(afL[l0s], tL.s, accL[nt], 0, 0, 0);
            accR[nt] = __builtin_amdgcn_mfma_f32_16x16x32_bf16(afR[l0s], tR.s, accR[nt], 0, 0, 0);
        }

    // bias + scatter C-layout -> bufL/bufR [l][d] fp32 (different LDS region: no hazard)
    float blv[4], brv[4];
#pragma unroll
    for (int r = 0; r < 4; ++r) {
        int krow = kw + quad * 4 + r;
        blv[r] = bl[krow]; brv[r] = br[krow];
    }
#pragma unroll
    for (int nt = 0; nt < 4; ++nt)
#pragma unroll
        for (int r = 0; r < 4; ++r) {
            int krow = kw + quad * 4 + r, col = nt * 16 + m16;
            bufL[krow][col] = accL[nt][r] + blv[r];
            bufR[krow][col] = accR[nt][r] + brv[r];
        }
    __syncthreads();   // staging reads done everywhere; bufL/R visible

    // ---- P3: merged, balanced corr (1024 FMAs/thread) -> corrT (bf16, swizzled)
    float Rr[64];
#pragma unroll
    for (int j = 0; j < 64; ++j) Rr[j] = bufR[j][lane];

    float accA[16], accB[16];
    switch (w) {
        case 0: corrAB<0>(bufL, Rr, accA, accB, lane); break;
        case 1: corrAB<1>(bufL, Rr, accA, accB, lane); break;
        case 2: corrAB<2>(bufL, Rr, accA, accB, lane); break;
        default: corrAB<3>(bufL, Rr, accA, accB, lane); break;
    }
    // write 4 swizzled b128 stores: cols [kw,kw+16) -> groups {2w,2w+1}; +64 -> {8+2w,8+2w+1}
    {
        const float* srcs[4] = { accA, accA + 8, accB, accB + 8 };
        const int grps[4] = { 2 * w, 2 * w + 1, 8 + 2 * w, 8 + 2 * w + 1 };
#pragma unroll
        for (int s = 0; s < 4; ++s) {
            short8 v;
#pragma unroll
            for (int j = 0; j < 8; ++j) v[j] = colvalid ? (short)f2bf(srcs[s][j]) : (short)0;
            int phys = grps[s] ^ (lane & 7);
            *(short8*)&corrT[lane * 128 + phys * 8] = v;
        }
    }
    __syncthreads();

    // ---- P4: conv via MFMA over all 128 c (3 taps x 4 c-groups x 4 n-tiles)
    short8 af[12];
#pragma unroll
    for (int t = 0; t < 3; ++t)
#pragma unroll
        for (int qi = 0; qi < 4; ++qi) {
            if (PRE) {
                af[t * 4 + qi] = ((const short8*)W2)[((t * 4 + qi) * 4 + w) * 64 + lane];
            } else {
                const float* p = Wconv + ((kw + m16) * 128 + 32 * qi + 8 * quad) * 3 + t;
#pragma unroll
                for (int j = 0; j < 8; ++j) af[t * 4 + qi][j] = (short)f2bf(p[3 * j]);
            }
        }
    float4_ yacc[4];
#pragma unroll
    for (int nt = 0; nt < 4; ++nt) yacc[nt] = (float4_){0,0,0,0};
#pragma unroll
    for (int t = 0; t < 3; ++t)
#pragma unroll
        for (int qi = 0; qi < 4; ++qi)
#pragma unroll
            for (int nt = 0; nt < 4; ++nt) {
                int row  = nt * 16 + m16 + t;                 // 0..65 (64,65 zeroed halo)
                int phys = (4 * qi + quad) ^ (row & 7);
                short8 bf = *(const short8*)&corrT[row * 128 + phys * 8];
                yacc[nt] = __builtin_amdgcn_mfma_f32_16x16x32_bf16(af[t * 4 + qi], bf,
                                                                   yacc[nt], 0, 0, 0);
            }

    // ---- P5: store y[b,k,d]  (D layout: col=lane&15 -> d, row=quad*4+r -> k)
#pragma unroll
    for (int nt = 0; nt < 4; ++nt) {
        const int dd = nt * 16 + m16;
        if (dd < ncols) {
#pragma unroll
            for (int r = 0; r < 4; ++r) {
                int k = kw + 4 * quad + r;
                out[((size_t)b * 64 + k) * DD + d_start + dd] = yacc[nt][r];
            }
        }
    }
}

extern "C" void kernel_launch(void* const* d_in, const int* in_sizes, int n_in,
                              void* d_out, int out_size, void* d_ws, size_t ws_size,
                              hipStream_t stream) {
    const float* left  = (const float*)d_in[0];
    const float* right = (const float*)d_in[1];
    const float* Wl    = (const float*)d_in[2];
    const float* bl    = (const float*)d_in[3];
    const float* Wr    = (const float*)d_in[4];
    const float* br    = (const float*)d_in[5];
    const float* Wconv = (const float*)d_in[6];
    float* out = (float*)d_out;

    dim3 grid(NTILE, BB);
    if (ws_size >= 32768 * sizeof(unsigned short)) {
        unsigned short* W2 = (unsigned short*)d_ws;
        prep_w<<<128, 256, 0, stream>>>(Wconv, Wl, Wr, W2);
        fused_cc_kernel<true><<<grid, dim3(256), 0, stream>>>(left, right, Wl, bl, Wr, br,
                                                              Wconv, W2, out);
    } else {
        fused_cc_kernel<false><<<grid, dim3(256), 0, stream>>>(left, right, Wl, bl, Wr, br,
                                                               Wconv, nullptr, out);
    }
}